// Round 4
// baseline (102.769 us; speedup 1.0000x reference)
//
#include <hip/hip_runtime.h>
#include <hip/hip_bf16.h>

using bf16x8 = __attribute__((ext_vector_type(8))) short;
using f32x4  = __attribute__((ext_vector_type(4))) float;

constexpr int N_ = 512;
constexpr int C_ = 32;

__device__ __forceinline__ short f2bf(float x) {
    return __builtin_bit_cast(short, __float2bfloat16(x));   // RNE
}
__device__ __forceinline__ unsigned pkbf(float lo, float hi) {
    unsigned a = (unsigned short)__builtin_bit_cast(short, __float2bfloat16(lo));
    unsigned b = (unsigned short)__builtin_bit_cast(short, __float2bfloat16(hi));
    return a | (b << 16);
}

struct Tile {
    f32x4 a0, a1;                   // rbf[k][8lg..8lg+7]
    float rx, ry, rz;               // rij[k]
    f32x4 f0, f1, f2v, g0, g1, g2;  // tensor[b,k,4lg..4lg+3,:], [.. +16 ..]
};

// Orientation: H' = mfma(A=W1, B=rbf^T) -> C'[ch][edge]; R' = mfma(A=W2, B=H).
// C-layout: lane(lg,lr) holds col i=lr (edge), rows m=4*lg+r (+16 hi tile).
__global__ __launch_bounds__(256, 4)
void filter_k4(const float* __restrict__ tensor,  // [B,N,C,3]
               const float* __restrict__ rbf,     // [B,N,N,32]
               const float* __restrict__ rij,     // [B,N,N,3]
               const float* __restrict__ W1,
               const float* __restrict__ b1,
               const float* __restrict__ W2,
               const float* __restrict__ b2,
               float* __restrict__ out)            // [B,N,C]
{
    const int bn   = blockIdx.x;
    const int b    = bn >> 9;
    const int tid  = threadIdx.x;
    const int lane = tid & 63;
    const int w    = tid >> 6;
    const int lr   = lane & 15;
    const int lg   = lane >> 4;

    // H packed as bf16-pair dwords: [wave][edge][dwrow=ch/2], stride 18 (pad).
    __shared__ unsigned Hpk[4][16][18];
    __shared__ float red2[4][32];

    // Weight A-fragments: lane holds row m=lr(+16), k=8*lg+e
    bf16x8 W1a[2], W2a[2];
    #pragma unroll
    for (int t = 0; t < 2; ++t) {
        const float* p1 = W1 + (lr + 16 * t) * 32 + 8 * lg;
        const float* p2 = W2 + (lr + 16 * t) * 32 + 8 * lg;
        const f32x4 x0 = ((const f32x4*)p1)[0], x1 = ((const f32x4*)p1)[1];
        const f32x4 y0 = ((const f32x4*)p2)[0], y1 = ((const f32x4*)p2)[1];
        #pragma unroll
        for (int e = 0; e < 4; ++e) {
            W1a[t][e] = f2bf(x0[e]); W1a[t][4 + e] = f2bf(x1[e]);
            W2a[t][e] = f2bf(y0[e]); W2a[t][4 + e] = f2bf(y1[e]);
        }
    }
    // Biases for C-layout rows this lane owns: m = 4*lg+r (+16)
    float b1lo[4], b1hi[4], b2lo[4], b2hi[4];
    #pragma unroll
    for (int r = 0; r < 4; ++r) {
        b1lo[r] = b1[4 * lg + r];  b1hi[r] = b1[16 + 4 * lg + r];
        b2lo[r] = b2[4 * lg + r];  b2hi[r] = b2[16 + 4 * lg + r];
    }

    const float* rbf_bn = rbf + (size_t)bn * (N_ * 32);
    const float* rij_bn = rij + (size_t)bn * (N_ * 3);
    const float* ten_b  = tensor + (size_t)b * (N_ * C_ * 3);

    auto load_tile = [&](int j, Tile& T) {
        const int k = (w * 8 + j) * 16 + lr;          // this lane's edge
        const float* ap = rbf_bn + (size_t)k * 32 + 8 * lg;
        T.a0 = ((const f32x4*)ap)[0];
        T.a1 = ((const f32x4*)ap)[1];
        T.rx = rij_bn[k * 3 + 0];
        T.ry = rij_bn[k * 3 + 1];
        T.rz = rij_bn[k * 3 + 2];
        const float* tp = ten_b + ((size_t)k * C_ + 4 * lg) * 3;  // 16B aligned
        T.f0 = ((const f32x4*)tp)[0];
        T.f1 = ((const f32x4*)tp)[1];
        T.f2v = ((const f32x4*)tp)[2];
        const float* tq = tp + 48;                                 // +16 channels
        T.g0 = ((const f32x4*)tq)[0];
        T.g1 = ((const f32x4*)tq)[1];
        T.g2 = ((const f32x4*)tq)[2];
    };

    float acc[8];
    #pragma unroll
    for (int c = 0; c < 8; ++c) acc[c] = 0.f;

    Tile cur, nxt;
    load_tile(0, cur);

    #pragma unroll
    for (int j = 0; j < 8; ++j) {
        // Prefetch next tile FIRST (before the lgkm fence) so the global
        // loads stay in flight across it and hide under this tile's compute.
        if (j < 7) load_tile(j + 1, nxt);

        // rbf B-fragment: lane holds col i=lr, k=8*lg+e
        bf16x8 X;
        #pragma unroll
        for (int e = 0; e < 4; ++e) { X[e] = f2bf(cur.a0[e]); X[4 + e] = f2bf(cur.a1[e]); }

        // Layer 1: H'[ch][edge]
        f32x4 h0 = {0, 0, 0, 0}, h1 = {0, 0, 0, 0};
        h0 = __builtin_amdgcn_mfma_f32_16x16x32_bf16(W1a[0], X, h0, 0, 0, 0);
        h1 = __builtin_amdgcn_mfma_f32_16x16x32_bf16(W1a[1], X, h1, 0, 0, 0);

        // bias+relu, pack to bf16 pairs, store: lane owns ch {4lg..4lg+3},
        // {16+4lg..}, edge lr -> dwrows {2lg,2lg+1} and {8+2lg,8+2lg+1}.
        const unsigned p0 = pkbf(fmaxf(h0[0] + b1lo[0], 0.f), fmaxf(h0[1] + b1lo[1], 0.f));
        const unsigned p1 = pkbf(fmaxf(h0[2] + b1lo[2], 0.f), fmaxf(h0[3] + b1lo[3], 0.f));
        const unsigned p2 = pkbf(fmaxf(h1[0] + b1hi[0], 0.f), fmaxf(h1[1] + b1hi[1], 0.f));
        const unsigned p3 = pkbf(fmaxf(h1[2] + b1hi[2], 0.f), fmaxf(h1[3] + b1hi[3], 0.f));
        *reinterpret_cast<uint2*>(&Hpk[w][lr][2 * lg])     = make_uint2(p0, p1);
        *reinterpret_cast<uint2*>(&Hpk[w][lr][8 + 2 * lg]) = make_uint2(p2, p3);

        // Cross-lane RAW within the wave: drain LDS writes only (vmcnt
        // untouched -> prefetch keeps flying). Pin reads below the fence.
        asm volatile("s_waitcnt lgkmcnt(0)" ::: "memory");
        __builtin_amdgcn_sched_barrier(0);

        // H B-fragment: ch 8lg..8lg+7 at edge lr = dwrows 4lg..4lg+3.
        const uint2 q0 = *reinterpret_cast<const uint2*>(&Hpk[w][lr][4 * lg]);
        const uint2 q1 = *reinterpret_cast<const uint2*>(&Hpk[w][lr][4 * lg + 2]);
        bf16x8 Hf;
        Hf[0] = (short)(q0.x & 0xFFFF); Hf[1] = (short)(q0.x >> 16);
        Hf[2] = (short)(q0.y & 0xFFFF); Hf[3] = (short)(q0.y >> 16);
        Hf[4] = (short)(q1.x & 0xFFFF); Hf[5] = (short)(q1.x >> 16);
        Hf[6] = (short)(q1.y & 0xFFFF); Hf[7] = (short)(q1.y >> 16);

        // Layer 2
        f32x4 r0 = {0, 0, 0, 0}, r1 = {0, 0, 0, 0};
        r0 = __builtin_amdgcn_mfma_f32_16x16x32_bf16(W2a[0], Hf, r0, 0, 0, 0);
        r1 = __builtin_amdgcn_mfma_f32_16x16x32_bf16(W2a[1], Hf, r1, 0, 0, 0);

        // Epilogue: one edge per lane (edge lr of this tile), 8 channels.
        const float rx = cur.rx, ry = cur.ry, rz = cur.rz;
        const float r2 = rx * rx + ry * ry + rz * rz;
        const float inv = rsqrtf(fmaxf(r2, 1e-8f));
        const float vm = (r2 >= 1e-16f) ? 1.f : 0.f;   // |rij| >= 1e-8
        const float s0 = (rx * cur.f0[0] + ry * cur.f0[1] + rz * cur.f0[2]) * inv;
        const float s1 = (rx * cur.f0[3] + ry * cur.f1[0] + rz * cur.f1[1]) * inv;
        const float s2 = (rx * cur.f1[2] + ry * cur.f1[3] + rz * cur.f2v[0]) * inv;
        const float s3 = (rx * cur.f2v[1] + ry * cur.f2v[2] + rz * cur.f2v[3]) * inv;
        const float t0 = (rx * cur.g0[0] + ry * cur.g0[1] + rz * cur.g0[2]) * inv;
        const float t1 = (rx * cur.g0[3] + ry * cur.g1[0] + rz * cur.g1[1]) * inv;
        const float t2 = (rx * cur.g1[2] + ry * cur.g1[3] + rz * cur.g2[0]) * inv;
        const float t3 = (rx * cur.g2[1] + ry * cur.g2[2] + rz * cur.g2[3]) * inv;
        acc[0] += vm * (r0[0] + b2lo[0]) * s0;
        acc[1] += vm * (r0[1] + b2lo[1]) * s1;
        acc[2] += vm * (r0[2] + b2lo[2]) * s2;
        acc[3] += vm * (r0[3] + b2lo[3]) * s3;
        acc[4] += vm * (r1[0] + b2hi[0]) * t0;
        acc[5] += vm * (r1[1] + b2hi[1]) * t1;
        acc[6] += vm * (r1[2] + b2hi[2]) * t2;
        acc[7] += vm * (r1[3] + b2hi[3]) * t3;

        cur = nxt;   // register rename under full unroll
    }

    // Reduce over the 16 edges (lr lanes) within each 16-lane group.
    #pragma unroll
    for (int c = 0; c < 8; ++c) {
        #pragma unroll
        for (int msk = 1; msk < 16; msk <<= 1)
            acc[c] += __shfl_xor(acc[c], msk, 64);
    }
    if (lr == 0) {
        #pragma unroll
        for (int r = 0; r < 4; ++r) {
            red2[w][4 * lg + r]      = acc[r];
            red2[w][16 + 4 * lg + r] = acc[4 + r];
        }
    }
    __syncthreads();
    if (tid < 32) {
        float t = 0.f;
        #pragma unroll
        for (int ww = 0; ww < 4; ++ww) t += red2[ww][tid];
        out[bn * C_ + tid] = t;
    }
}

extern "C" void kernel_launch(void* const* d_in, const int* in_sizes, int n_in,
                              void* d_out, int out_size, void* d_ws, size_t ws_size,
                              hipStream_t stream) {
    const float* tensor = (const float*)d_in[0];
    const float* rbf    = (const float*)d_in[1];
    const float* rij    = (const float*)d_in[2];
    const float* W1     = (const float*)d_in[3];
    const float* b1     = (const float*)d_in[4];
    const float* W2     = (const float*)d_in[5];
    const float* b2     = (const float*)d_in[6];
    float* out = (float*)d_out;

    dim3 grid(2 * N_), block(256);
    filter_k4<<<grid, block, 0, stream>>>(tensor, rbf, rij, W1, b1, W2, b2, out);
}

// Round 6
// 47.176 us; speedup vs baseline: 2.1784x; 2.1784x over previous
//
#include <hip/hip_runtime.h>
#include <hip/hip_bf16.h>

using bf16x8 = __attribute__((ext_vector_type(8))) short;
using f32x4  = __attribute__((ext_vector_type(4))) float;
using f32x16 = __attribute__((ext_vector_type(16))) float;
using u32x4  = __attribute__((ext_vector_type(4))) unsigned;

constexpr int N_ = 512;
constexpr int C_ = 32;

__device__ __forceinline__ unsigned pkbf(float lo, float hi) {
    unsigned a = (unsigned short)__builtin_bit_cast(short, __float2bfloat16(lo));
    unsigned b = (unsigned short)__builtin_bit_cast(short, __float2bfloat16(hi));
    return a | (b << 16);
}

// 32x32x16 MFMA whole-tile formulation. Per 32-edge tile:
//   H' = W1 @ rbf^T (2 MFMA, K=32). C-layout: col=edge(l), row=(i&3)+8*(i>>2)+4*l5.
//   Re-layout H' -> layer-2 B-fragments: 8 cvt_pk + 8 shfl_xor(32) + 8 cndmask
//   (shfl_xor has unambiguous semantics, unlike permlane32_swap operand order).
//   R' = W2 @ H (2 MFMA). Epilogue per lane: 1 edge x 16 channels, f32x4 reads.
// No LDS / no fences in the loop -> compiler pipelines global loads freely.
__global__ __launch_bounds__(256, 3)
void filter_32(const float* __restrict__ tensor,  // [B,N,C,3]
               const float* __restrict__ rbf,     // [B,N,N,32]
               const float* __restrict__ rij,     // [B,N,N,3]
               const float* __restrict__ W1,
               const float* __restrict__ b1,
               const float* __restrict__ W2,
               const float* __restrict__ b2,
               float* __restrict__ out)            // [B,N,C]
{
    const int bn   = blockIdx.x;
    const int b    = bn >> 9;
    const int tid  = threadIdx.x;
    const int lane = tid & 63;
    const int w    = tid >> 6;
    const int l    = lane & 31;   // A-row / B-col / C-col
    const int l5   = lane >> 5;   // k-group (0,1)

    __shared__ float red[4][32];

    // Weight A-fragments: lane holds row m=l, k = 8*l5+e (frag0), 16+8*l5+e (frag1)
    bf16x8 W1a[2], W2a[2];
    {
        const float* p1 = W1 + l * 32 + 8 * l5;
        const float* p2 = W2 + l * 32 + 8 * l5;
        const f32x4 a0 = ((const f32x4*)p1)[0], a1 = ((const f32x4*)p1)[1];
        const f32x4 a2 = ((const f32x4*)(p1 + 16))[0], a3 = ((const f32x4*)(p1 + 16))[1];
        const f32x4 c0 = ((const f32x4*)p2)[0], c1 = ((const f32x4*)p2)[1];
        const f32x4 c2 = ((const f32x4*)(p2 + 16))[0], c3 = ((const f32x4*)(p2 + 16))[1];
        #pragma unroll
        for (int e = 0; e < 4; ++e) {
            W1a[0][e] = __builtin_bit_cast(short, __float2bfloat16(a0[e]));
            W1a[0][4 + e] = __builtin_bit_cast(short, __float2bfloat16(a1[e]));
            W1a[1][e] = __builtin_bit_cast(short, __float2bfloat16(a2[e]));
            W1a[1][4 + e] = __builtin_bit_cast(short, __float2bfloat16(a3[e]));
            W2a[0][e] = __builtin_bit_cast(short, __float2bfloat16(c0[e]));
            W2a[0][4 + e] = __builtin_bit_cast(short, __float2bfloat16(c1[e]));
            W2a[1][e] = __builtin_bit_cast(short, __float2bfloat16(c2[e]));
            W2a[1][4 + e] = __builtin_bit_cast(short, __float2bfloat16(c3[e]));
        }
    }
    // Biases for this lane's C-layout rows: chunk q -> rows 8q+4*l5 .. +3 (16B-aligned)
    f32x4 b1v[4], b2v[4];
    #pragma unroll
    for (int q = 0; q < 4; ++q) {
        b1v[q] = *(const f32x4*)(b1 + 8 * q + 4 * l5);
        b2v[q] = *(const f32x4*)(b2 + 8 * q + 4 * l5);
    }

    const float* rbf_bn = rbf + (size_t)bn * (N_ * 32);
    const float* rij_bn = rij + (size_t)bn * (N_ * 3);
    const float* ten_b  = tensor + (size_t)b * (N_ * C_ * 3);

    f32x16 accO;
    #pragma unroll
    for (int i = 0; i < 16; ++i) accO[i] = 0.f;

    #pragma unroll
    for (int j = 0; j < 4; ++j) {
        const int e0 = (w * 4 + j) * 32;
        const int k  = e0 + l;                 // this lane's edge

        // rbf B-fragments: lane col=edge k, k-dim 8*l5+e / 16+8*l5+e
        const float* ap = rbf_bn + (size_t)k * 32 + 8 * l5;
        const f32x4 x0 = ((const f32x4*)ap)[0];
        const f32x4 x1 = ((const f32x4*)ap)[1];
        const f32x4 x2 = ((const f32x4*)(ap + 16))[0];
        const f32x4 x3 = ((const f32x4*)(ap + 16))[1];
        // epilogue operands (independent loads, schedule freely)
        const float rx = rij_bn[k * 3 + 0];
        const float ry = rij_bn[k * 3 + 1];
        const float rz = rij_bn[k * 3 + 2];
        const float* tp = ten_b + ((size_t)k * 32 + 4 * l5) * 3;

        bf16x8 X0, X1;
        #pragma unroll
        for (int e = 0; e < 4; ++e) {
            X0[e]     = __builtin_bit_cast(short, __float2bfloat16(x0[e]));
            X0[4 + e] = __builtin_bit_cast(short, __float2bfloat16(x1[e]));
            X1[e]     = __builtin_bit_cast(short, __float2bfloat16(x2[e]));
            X1[4 + e] = __builtin_bit_cast(short, __float2bfloat16(x3[e]));
        }

        // Layer 1 (K=32 via 2 MFMAs into one acc)
        f32x16 h;
        #pragma unroll
        for (int i = 0; i < 16; ++i) h[i] = 0.f;
        h = __builtin_amdgcn_mfma_f32_32x32x16_bf16(W1a[0], X0, h, 0, 0, 0);
        h = __builtin_amdgcn_mfma_f32_32x32x16_bf16(W1a[1], X1, h, 0, 0, 0);

        // bias + relu + pack. Own channel pairs:
        //   pk(2q)   = ch(8q+4l5+0, 8q+4l5+1); pk(2q+1) = ch(8q+4l5+2, 8q+4l5+3)
        unsigned pk0, pk1, pk2, pk3, pk4, pk5, pk6, pk7;
        {
            const float h0 = fmaxf(h[0] + b1v[0][0], 0.f), h1 = fmaxf(h[1] + b1v[0][1], 0.f);
            const float h2 = fmaxf(h[2] + b1v[0][2], 0.f), h3 = fmaxf(h[3] + b1v[0][3], 0.f);
            const float h4 = fmaxf(h[4] + b1v[1][0], 0.f), h5 = fmaxf(h[5] + b1v[1][1], 0.f);
            const float h6 = fmaxf(h[6] + b1v[1][2], 0.f), h7 = fmaxf(h[7] + b1v[1][3], 0.f);
            const float h8 = fmaxf(h[8] + b1v[2][0], 0.f), h9 = fmaxf(h[9] + b1v[2][1], 0.f);
            const float hA = fmaxf(h[10] + b1v[2][2], 0.f), hB = fmaxf(h[11] + b1v[2][3], 0.f);
            const float hC = fmaxf(h[12] + b1v[3][0], 0.f), hD = fmaxf(h[13] + b1v[3][1], 0.f);
            const float hE = fmaxf(h[14] + b1v[3][2], 0.f), hF = fmaxf(h[15] + b1v[3][3], 0.f);
            pk0 = pkbf(h0, h1); pk1 = pkbf(h2, h3);
            pk2 = pkbf(h4, h5); pk3 = pkbf(h6, h7);
            pk4 = pkbf(h8, h9); pk5 = pkbf(hA, hB);
            pk6 = pkbf(hC, hD); pk7 = pkbf(hE, hF);
        }
        // Half-exchange with unambiguous shfl_xor(32). Needed B-fragment dwords
        // (k = 8*l5+e for Hf1, 16+8*l5+e for Hf2), x^ = partner's value:
        //   Hf1 = { l5?pk2^:pk0, l5?pk3^:pk1, l5?pk2:pk0^, l5?pk3:pk1^ }
        const unsigned q0 = __shfl_xor(pk0, 32, 64);
        const unsigned q1 = __shfl_xor(pk1, 32, 64);
        const unsigned q2 = __shfl_xor(pk2, 32, 64);
        const unsigned q3 = __shfl_xor(pk3, 32, 64);
        const unsigned q4 = __shfl_xor(pk4, 32, 64);
        const unsigned q5 = __shfl_xor(pk5, 32, 64);
        const unsigned q6 = __shfl_xor(pk6, 32, 64);
        const unsigned q7 = __shfl_xor(pk7, 32, 64);
        const bool lo = (l5 == 0);
        const u32x4 f1d = { lo ? pk0 : q2, lo ? pk1 : q3, lo ? q0 : pk2, lo ? q1 : pk3 };
        const u32x4 f2d = { lo ? pk4 : q6, lo ? pk5 : q7, lo ? q4 : pk6, lo ? q5 : pk7 };
        const bf16x8 Hf1 = __builtin_bit_cast(bf16x8, f1d);
        const bf16x8 Hf2 = __builtin_bit_cast(bf16x8, f2d);

        // Layer 2
        f32x16 rr;
        #pragma unroll
        for (int i = 0; i < 16; ++i) rr[i] = 0.f;
        rr = __builtin_amdgcn_mfma_f32_32x32x16_bf16(W2a[0], Hf1, rr, 0, 0, 0);
        rr = __builtin_amdgcn_mfma_f32_32x32x16_bf16(W2a[1], Hf2, rr, 0, 0, 0);

        // Epilogue: lane's edge k, channel rows 8q+4l5+r
        const float r2v = rx * rx + ry * ry + rz * rz;
        const float inv = rsqrtf(fmaxf(r2v, 1e-8f));
        const float vm  = (r2v >= 1e-16f) ? 1.f : 0.f;   // |rij| >= 1e-8
        #pragma unroll
        for (int q = 0; q < 4; ++q) {
            const f32x4 g0 = ((const f32x4*)(tp + 24 * q))[0];
            const f32x4 g1 = ((const f32x4*)(tp + 24 * q))[1];
            const f32x4 g2 = ((const f32x4*)(tp + 24 * q))[2];
            const float s0 = (rx * g0[0] + ry * g0[1] + rz * g0[2]) * inv;
            const float sv1 = (rx * g0[3] + ry * g1[0] + rz * g1[1]) * inv;
            const float sv2 = (rx * g1[2] + ry * g1[3] + rz * g2[0]) * inv;
            const float sv3 = (rx * g2[1] + ry * g2[2] + rz * g2[3]) * inv;
            accO[4 * q + 0] += vm * (rr[4 * q + 0] + b2v[q][0]) * s0;
            accO[4 * q + 1] += vm * (rr[4 * q + 1] + b2v[q][1]) * sv1;
            accO[4 * q + 2] += vm * (rr[4 * q + 2] + b2v[q][2]) * sv2;
            accO[4 * q + 3] += vm * (rr[4 * q + 3] + b2v[q][3]) * sv3;
        }
    }

    // Butterfly all-reduce over the 32 edge-columns (closed within each half).
    #pragma unroll
    for (int i = 0; i < 16; ++i) {
        float v = accO[i];
        #pragma unroll
        for (int m = 1; m <= 16; m <<= 1) v += __shfl_xor(v, m, 64);
        accO[i] = v;
    }
    if (l == 0) {   // lanes 0 and 32: disjoint row sets
        #pragma unroll
        for (int q = 0; q < 4; ++q) {
            red[w][8 * q + 4 * l5 + 0] = accO[4 * q + 0];
            red[w][8 * q + 4 * l5 + 1] = accO[4 * q + 1];
            red[w][8 * q + 4 * l5 + 2] = accO[4 * q + 2];
            red[w][8 * q + 4 * l5 + 3] = accO[4 * q + 3];
        }
    }
    __syncthreads();
    if (tid < 32) {
        out[bn * C_ + tid] = red[0][tid] + red[1][tid] + red[2][tid] + red[3][tid];
    }
}

extern "C" void kernel_launch(void* const* d_in, const int* in_sizes, int n_in,
                              void* d_out, int out_size, void* d_ws, size_t ws_size,
                              hipStream_t stream) {
    const float* tensor = (const float*)d_in[0];
    const float* rbf    = (const float*)d_in[1];
    const float* rij    = (const float*)d_in[2];
    const float* W1     = (const float*)d_in[3];
    const float* b1     = (const float*)d_in[4];
    const float* W2     = (const float*)d_in[5];
    const float* b2     = (const float*)d_in[6];
    float* out = (float*)d_out;

    dim3 grid(2 * N_), block(256);
    filter_32<<<grid, block, 0, stream>>>(tensor, rbf, rij, W1, b1, W2, b2, out);
}